// Round 16
// baseline (316.153 us; speedup 1.0000x reference)
//
#include <hip/hip_runtime.h>

#define IN_C 128
#define OUT_C 64
#define PAD 8            // degree padded to multiple of 8 -> fixed 8-deep gather groups
typedef long long ll;

// ---------------- fused: register-tile GEMM (y0 = x @ W.T)  ||  edge count ----------------
// gemm role: lane = out-channel; W row in 128 VGPRs (small loop body keeps it resident);
// x rows via wave-uniform global float4 loads (L1 broadcast). No LDS, no syncthreads.
// count role (blocks >= nGemm): per-edge atomicAdd histogram. Independent work.

__global__ __launch_bounds__(256) void k_fused_gc(const float* __restrict__ x,
                                                  const float* __restrict__ W,
                                                  float* __restrict__ y0,
                                                  const int* __restrict__ dst,
                                                  int* __restrict__ cnt,
                                                  int nGemm, int E) {
    if ((int)blockIdx.x >= nGemm) {               // ---- count role ----
        int e = (blockIdx.x - nGemm) * 256 + threadIdx.x;
        if (e < E) atomicAdd(&cnt[dst[e]], 1);
        return;
    }
    // ---- gemm role ----
    int tid  = threadIdx.x;
    int lane = tid & 63;                          // lane == output channel
    int wid  = tid >> 6;                          // 0..3
    int r0   = (blockIdx.x << 6) + (wid << 4);    // this wave's 16 rows

    float4 wreg[32];                              // W row for this lane: 128 VGPRs
    const float4* W4 = (const float4*)(W + (ll)lane * IN_C);
    #pragma unroll
    for (int q = 0; q < 32; ++q) wreg[q] = W4[q];

    #pragma unroll 2
    for (int rr = 0; rr < 16; ++rr) {
        const float4* xq = (const float4*)(x + (ll)(r0 + rr) * IN_C);
        float a0 = 0.f, a1 = 0.f, a2 = 0.f, a3 = 0.f;
        #pragma unroll
        for (int q = 0; q < 32; ++q) {
            float4 xv = xq[q];                    // uniform addr -> one L1 txn, broadcast
            float4 wv = wreg[q];
            a0 += xv.x * wv.x; a1 += xv.y * wv.y;
            a2 += xv.z * wv.z; a3 += xv.w * wv.w;
        }
        y0[(ll)(r0 + rr) * OUT_C + lane] = (a0 + a1) + (a2 + a3);  // coalesced
    }
}

// ---------------- CSR build ----------------

// Allocate padded slot ranges (one atomic per wave via scan), write meta+dinv,
// convert cnt[] into cursor[], and pre-fill pad slots with (col=i, w=0).
__global__ __launch_bounds__(256) void k_alloc(int* __restrict__ cnt_cursor,
                                               int4* __restrict__ meta,
                                               float* __restrict__ dinv,
                                               int2* __restrict__ wcol,
                                               int* __restrict__ total, int N) {
    int i    = blockIdx.x * 256 + threadIdx.x;
    int lane = threadIdx.x & 63;
    int c  = (i < N) ? cnt_cursor[i] : 0;
    int c8 = (c + PAD - 1) & ~(PAD - 1);
    int scan = c8;                       // inclusive wave scan
    #pragma unroll
    for (int d = 1; d < 64; d <<= 1) {
        int t = __shfl_up(scan, d);
        if (lane >= d) scan += t;
    }
    int wave_total = __shfl(scan, 63);
    int base = 0;
    if (lane == 63) base = atomicAdd(total, wave_total);
    base = __shfl(base, 63);
    if (i < N) {
        int s = base + scan - c8;        // exclusive prefix
        float dv = 1.0f / sqrtf((float)(c + 1));   // +1 self-loop
        meta[i] = make_int4(s, c8, __float_as_int(dv), 0);
        dinv[i] = dv;
        cnt_cursor[i] = s;               // becomes fill cursor
        for (int p = s + c; p < s + c8; ++p)       // <=7 pad slots
            wcol[p] = make_int2(i, 0);   // w bits 0 == 0.0f
    }
}

// Fill slots with (src, precomputed weight dinv[src]*dinv[dst]).
__global__ __launch_bounds__(256) void k_fill(const int* __restrict__ src,
                                              const int* __restrict__ dst,
                                              int* __restrict__ cursor,
                                              const float* __restrict__ dinv,
                                              int2* __restrict__ wcol, int E) {
    int e = blockIdx.x * 256 + threadIdx.x;
    if (e < E) {
        int s = src[e], d = dst[e];
        int p = atomicAdd(&cursor[d], 1);
        float w = dinv[s] * dinv[d];
        wcol[p] = make_int2(s, __float_as_int(w));
    }
}

// ---------------- 64-channel gather core ----------------
// acc = di^2 * h[i][lane] + sum_slots w * h[col][lane];  pad slots have w=0.

struct G8 { float u[8]; float w[8]; };

__device__ __forceinline__ void g8_issue(G8& g, const float* __restrict__ hin,
                                         int2 slot, int off, int lane) {
    int j[8];
    #pragma unroll
    for (int k = 0; k < 8; ++k) {
        j[k]   = __builtin_amdgcn_readlane(slot.x, off + k);                 // SGPR idx ok
        g.w[k] = __int_as_float(__builtin_amdgcn_readlane(slot.y, off + k));
    }
    #pragma unroll
    for (int k = 0; k < 8; ++k) g.u[k] = hin[(ll)j[k] * OUT_C + lane];       // 8 in flight
}

__device__ __forceinline__ void g8_acc(const G8& g, float& a0, float& a1) {
    #pragma unroll
    for (int k = 0; k < 8; ++k) {
        if (k & 1) a1 += g.w[k] * g.u[k]; else a0 += g.w[k] * g.u[k];
    }
}

// generic fallback (any c8, incl. >64)
__device__ __forceinline__ float gather64(const float* __restrict__ hin,
                                          const int2* __restrict__ wcol,
                                          int s, int c8, float di, int i, int lane) {
    float v  = hin[(ll)i * OUT_C + lane];
    float a0 = di * di * v, a1 = 0.f;
    for (int base = 0; base < c8; base += 64) {
        int nb = min(64, c8 - base);
        int2 sl = wcol[s + base + lane];
        for (int g = 0; g < nb; g += 8) {
            G8 gg;
            g8_issue(gg, hin, sl, g, lane);
            g8_acc(gg, a0, a1);
        }
    }
    return a0 + a1;
}

// pair-interleaved hop: 2 nodes per iteration -> 16-32 loads in flight
__device__ __forceinline__ void hop_pair(const float* __restrict__ hin,
                                         const int2* __restrict__ wcol,
                                         const int4* __restrict__ meta,
                                         float* __restrict__ hout,
                                         int N, int w0, int nw, int lane, float bias) {
    for (int ii = w0; ii < N; ii += 2 * nw) {
        int iA = __builtin_amdgcn_readfirstlane(ii);
        int ib = ii + nw;
        if (ib < N) {
            int iB = __builtin_amdgcn_readfirstlane(ib);
            int4 mA = meta[iA];
            int4 mB = meta[iB];
            int sA = mA.x, c8A = mA.y; float dA = __int_as_float(mA.z);
            int sB = mB.x, c8B = mB.y; float dB = __int_as_float(mB.z);
            if (c8A <= 64 && c8B <= 64) {          // covers ~100% (deg ~Poisson(10))
                int2 slA = wcol[sA + lane];        // both slot loads issued together
                int2 slB = wcol[sB + lane];
                float vA = hin[(ll)iA * OUT_C + lane];
                float vB = hin[(ll)iB * OUT_C + lane];
                float aA0 = dA * dA * vA, aA1 = 0.f;
                float aB0 = dB * dB * vB, aB1 = 0.f;
                int nA = c8A >> 3, nB = c8B >> 3;  // 8-batches per node
                int nmax = nA > nB ? nA : nB;
                for (int t = 0; t < nmax; ++t) {   // uniform loop, scalar branches
                    G8 ga, gb;
                    bool doA = t < nA, doB = t < nB;
                    if (doA) g8_issue(ga, hin, slA, t << 3, lane);
                    if (doB) g8_issue(gb, hin, slB, t << 3, lane);   // 16 in flight
                    if (doA) g8_acc(ga, aA0, aA1);
                    if (doB) g8_acc(gb, aB0, aB1);
                }
                hout[(ll)iA * OUT_C + lane] = aA0 + aA1 + bias;
                hout[(ll)iB * OUT_C + lane] = aB0 + aB1 + bias;
            } else {
                float aA = gather64(hin, wcol, sA, c8A, dA, iA, lane);
                float aB = gather64(hin, wcol, sB, c8B, dB, iB, lane);
                hout[(ll)iA * OUT_C + lane] = aA + bias;
                hout[(ll)iB * OUT_C + lane] = aB + bias;
            }
        } else {
            int4 m = meta[iA];
            float acc = gather64(hin, wcol, m.x, m.y, __int_as_float(m.z), iA, lane);
            hout[(ll)iA * OUT_C + lane] = acc + bias;
        }
    }
}

__global__ __launch_bounds__(256) void k_hop64(const float* __restrict__ hin,
                                               const int2* __restrict__ wcol,
                                               const int4* __restrict__ meta,
                                               float* __restrict__ hout, int N) {
    int lane = threadIdx.x & 63;
    int w0 = (blockIdx.x * blockDim.x + threadIdx.x) >> 6;
    int nw = (gridDim.x * blockDim.x) >> 6;
    hop_pair(hin, wcol, meta, hout, N, w0, nw, lane, 0.f);
}

__global__ __launch_bounds__(256) void k_hop64_bias(const float* __restrict__ hin,
                                                    const int2* __restrict__ wcol,
                                                    const int4* __restrict__ meta,
                                                    const float* __restrict__ b,
                                                    float* __restrict__ out, int N) {
    int lane = threadIdx.x & 63;
    int w0 = (blockIdx.x * blockDim.x + threadIdx.x) >> 6;
    int nw = (gridDim.x * blockDim.x) >> 6;
    hop_pair(hin, wcol, meta, out, N, w0, nw, lane, b[lane]);
}

// ---------------- launcher ----------------

extern "C" void kernel_launch(void* const* d_in, const int* in_sizes, int n_in,
                              void* d_out, int out_size, void* d_ws, size_t ws_size,
                              hipStream_t stream) {
    const float* x  = (const float*)d_in[0];
    const int*   ei = (const int*)d_in[1];
    const float* W  = (const float*)d_in[2];
    const float* b  = (const float*)d_in[3];
    float* out = (float*)d_out;

    int N = in_sizes[0] / IN_C;      // 65536
    int E = in_sizes[1] / 2;         // 655360
    const int* src = ei;
    const int* dst = ei + E;

    // workspace layout
    size_t cap_slots = (size_t)E + (size_t)PAD * N + 64;      // padded CSR + read guard
    size_t off_total = (size_t)N * 4;                          // cnt at 0, total after
    size_t off_meta  = ((off_total + 4 + 255) & ~(size_t)255); // N int4
    size_t off_dinv  = off_meta + (size_t)N * 16;              // N f32
    size_t off_wcol  = off_dinv + (size_t)N * 4;               // cap_slots int2
    size_t off_y0    = ((off_wcol + cap_slots * 8 + 255) & ~(size_t)255); // N*64 f32
    size_t off_h1    = off_y0 + (size_t)N * OUT_C * 4;         // N*64 f32
    size_t need      = off_h1 + (size_t)N * OUT_C * 4;
    if (ws_size < need) return;      // refuse to scribble OOB

    char* ws = (char*)d_ws;
    int*   cnt_cursor = (int*)(ws);
    int*   total      = (int*)(ws + off_total);
    int4*  meta       = (int4*)(ws + off_meta);
    float* dinv       = (float*)(ws + off_dinv);
    int2*  wcol       = (int2*)(ws + off_wcol);
    float* y0         = (float*)(ws + off_y0);
    float* h1         = (float*)(ws + off_h1);

    hipMemsetAsync(ws, 0, off_total + 4, stream);   // cnt + total

    int nGemm  = N >> 6;                 // 1024 (N%64==0)
    int nCount = (E + 255) / 256;        // 2560
    int gn     = (N + 255) / 256;

    k_fused_gc<<<nGemm + nCount, 256, 0, stream>>>(x, W, y0, dst, cnt_cursor, nGemm, E);
    k_alloc   <<<gn, 256, 0, stream>>>(cnt_cursor, meta, dinv, wcol, total, N);
    k_fill    <<<nCount, 256, 0, stream>>>(src, dst, cnt_cursor, dinv, wcol, E);

    k_hop64     <<<4096, 256, 0, stream>>>(y0, wcol, meta, h1, N);
    k_hop64_bias<<<4096, 256, 0, stream>>>(h1, wcol, meta, b, out, N);
}